// Round 22
// baseline (36.665 us; speedup 1.0000x reference)
//
#include <hip/hip_runtime.h>
#include <hip/hip_bf16.h>

// BasicBlock (ReActNet) fused pipeline, MI355X gfx950.  R22 = R21 (35.8us) +
// prologue-B fully unrolled IN ISOLATION (R20 bundled it with the 18-phase
// re-chunk that regressed via in-loop register pressure; the unroll itself is
// prologue-only pressure). All 12 x float4 loads issue before first consumer
// -> 6 serial ~700cy latency rounds collapse to ~1-2.
// Everything else identical to R21: fp4 MX MFMA, XCD swizzle, x-LDS residual.

typedef unsigned short u16;
typedef unsigned char  u8;
typedef unsigned int   u32;
typedef unsigned long long u64;
typedef float f32x4 __attribute__((ext_vector_type(4)));
typedef long  long2v __attribute__((ext_vector_type(2)));
typedef int   v8i  __attribute__((ext_vector_type(8)));
typedef float v16f __attribute__((ext_vector_type(16)));

__device__ __forceinline__ float b2f(u16 u) {
  union { unsigned int i; float f; } c; c.i = ((unsigned int)u) << 16; return c.f;
}
__device__ __forceinline__ u16 f2b(float f) {
  unsigned int u = __builtin_bit_cast(unsigned int, f);
  unsigned int r = (u + 0x7FFFu + ((u >> 16) & 1u)) >> 16;   // RNE
  return (u16)r;
}
__device__ __forceinline__ u32 f2sign4(float v) {  // fp4 e2m1 of sign(v)
  return (v > 0.f) ? 0x2u : ((v < 0.f) ? 0xAu : 0x0u);
}
__device__ __forceinline__ v8i mkv8(long2v a, long2v b) {
  union { long2v l[2]; v8i v; } u; u.l[0] = a; u.l[1] = b; return u.v;
}

// ---- prep: fp4 sign weights (nibble-packed, k-ascending), BN fold, loss ----
__global__ __launch_bounds__(256) void prep_kernel(
    const float* __restrict__ w1, const float* __restrict__ w2,
    const float* __restrict__ g1, const float* __restrict__ be1,
    const float* __restrict__ m1, const float* __restrict__ v1,
    const float* __restrict__ g2, const float* __restrict__ be2,
    const float* __restrict__ m2, const float* __restrict__ v2,
    u8* __restrict__ w1T, u8* __restrict__ w2T,
    float* __restrict__ ab,
    float* __restrict__ lossdst, const float* __restrict__ lossin)
{
  __shared__ float wrow[2304];
  __shared__ float red[256];
  const int t = threadIdx.x;
  const int blk = blockIdx.x;
  float s = 0.f;
  if (blk < 256) {                       // w1 row o: stage coalesced, then pack
    const int o = blk;
    const float4* src = (const float4*)(w1 + o * 2304);
#pragma unroll
    for (int i = 0; i < 3; ++i) {
      int c = i * 256 + t;
      if (c < 576) {
        float4 v = src[c];
        wrow[c * 4 + 0] = v.x; wrow[c * 4 + 1] = v.y;
        wrow[c * 4 + 2] = v.z; wrow[c * 4 + 3] = v.w;
        s += fabsf(v.x) + fabsf(v.y) + fabsf(v.z) + fabsf(v.w);
      }
    }
  } else {
    const int o = blk - 256;
    float v = w2[o * 256 + t];
    wrow[t] = v;
    s = fabsf(v);
  }
  red[t] = s;
  __syncthreads();
  for (int st = 128; st > 0; st >>= 1) { if (t < st) red[t] += red[t + st]; __syncthreads(); }
  if (blk < 256) {
    const int o = blk;
    for (int it = t; it < 288; it += 256) {   // (tap, ci-octet)
      int tap = it >> 5, ci8 = it & 31;
      u32 pack = 0;
#pragma unroll
      for (int k = 0; k < 8; ++k)
        pack |= f2sign4(wrow[(ci8 * 8 + k) * 9 + tap]) << (4 * k);
      int c64 = ci8 >> 3, kh = (ci8 >> 2) & 1, slot = ci8 & 3;
      *(u32*)(w1T + (size_t)((tap * 4 + c64) * 2 + kh) * 4096 + o * 16 + slot * 4) = pack;
    }
    if (t == 0) {
      float scale = red[0] / 2304.f;
      float inv = g1[o] / sqrtf(v1[o] + 1e-5f);
      ab[o]       = scale * inv;
      ab[256 + o] = be1[o] - m1[o] * inv;
    }
  } else {
    const int o = blk - 256;
    if (t < 32) {
      u32 pack = 0;
#pragma unroll
      for (int k = 0; k < 8; ++k)
        pack |= f2sign4(wrow[t * 8 + k]) << (4 * k);
      int c64 = t >> 3, kh = (t >> 2) & 1, slot = t & 3;
      *(u32*)(w2T + (size_t)(c64 * 2 + kh) * 4096 + o * 16 + slot * 4) = pack;
    }
    if (t == 0) {
      float scale = red[0] / 256.f;
      float inv = g2[o] / sqrtf(v2[o] + 1e-5f);
      ab[512 + o] = scale * inv;
      ab[768 + o] = be2[o] - m2[o] * inv;
    }
  }
  if (blk == 0 && t == 0) lossdst[0] = lossin[0];
}

// ---------------- fused: act1-window(fp4) + conv3x3 + conv1x1 ----------------
__global__ __launch_bounds__(512, 1) void fused_kernel(
    const float* __restrict__ x, const float* __restrict__ b11,
    const u8* __restrict__ w1T, const u8* __restrict__ w2T,
    const float* __restrict__ ab,
    const float* __restrict__ b12, const float* __restrict__ a1,
    const float* __restrict__ b13, const float* __restrict__ b21,
    const float* __restrict__ b22, const float* __restrict__ a2,
    const float* __restrict__ b23,
    float* __restrict__ dout)
{
  // shmem: [0..26112) fp4 window/act2 ; [26112..144896) xbuf [256 och][116 f32]
  // (xbuf re-aliased as out-transpose buffer after the post-conv1x1 barrier).
  __shared__ __align__(16) u8 shmem[144928];
  __shared__ float bsh[256];

  const int t = threadIdx.x;
  const int w = t >> 6;
  const int l = t & 63;
  const int l31 = l & 31;
  const int h32 = l >> 5;              // k-half selector
  const int mg = w & 1;                // m-pair group
  const int ng = w >> 1;               // och quad (64 och)
  // XCD-aware swizzle (224 = 8*28, bijective): each XCD gets 28 contiguous
  // logical blocks (4 whole images) -> halo-sharing neighbors share an L2.
  const int pxblk = (blockIdx.x & 7) * 28 + (blockIdx.x >> 3);
  const int img = pxblk / 7;
  const int rowgrp = pxblk % 7;

  // per-lane epilogue params for nf = 0,1
  float al1[2], bt1[2], pA1[2], pS1[2], pB1[2], p21[2];
  float al2[2], bt2[2], pA2[2], pS2[2], pB2[2];
  int Ov[2];
#pragma unroll
  for (int nf = 0; nf < 2; ++nf) {
    int O = ng * 64 + nf * 32 + l31;
    Ov[nf] = O;
    al1[nf] = ab[O];       bt1[nf] = ab[256 + O];
    al2[nf] = ab[512 + O]; bt2[nf] = ab[768 + O];
    pA1[nf] = b12[O]; pS1[nf] = a1[O]; pB1[nf] = b13[O]; p21[nf] = b21[O];
    pA2[nf] = b22[O]; pS2[nf] = a2[O]; pB2[nf] = b23[O];
  }

  int basepix[2];
#pragma unroll
  for (int mi = 0; mi < 2; ++mi) {
    int pm = (mg * 2 + mi) * 32 + l31;
    int r = (pm * 293) >> 13;          // pm/28
    basepix[mi] = r * 30 + (pm - 28 * r);
  }

  char* wl = (char*)shmem;
  float* xbuf = (float*)(shmem + 26112);   // [256][116]

  v16f acc[2][2];
  v16f zero16 = {0.f,0.f,0.f,0.f,0.f,0.f,0.f,0.f,0.f,0.f,0.f,0.f,0.f,0.f,0.f,0.f};
  f32x4 zero4 = {0.f, 0.f, 0.f, 0.f};
  long2v zl2 = {0, 0};
#pragma unroll
  for (int mi = 0; mi < 2; ++mi)
#pragma unroll
    for (int nf = 0; nf < 2; ++nf) acc[mi][nf] = zero16;

  // ---- prologue A: zero window (this IS the conv padding), stage b11 ----
  if (t < 256) bsh[t] = b11[t];
#pragma unroll
  for (int i = 0; i < 4; ++i) {
    int c = i * 512 + t;
    if (c < 1632) *(f32x4*)(wl + c * 16) = zero4;
  }
  __syncthreads();

  // ---- prologue B: act1 window from x -> fp4 nibbles (XOR-swizzled);
  //      own-block rows also stashed raw f32 into xbuf[och][116].
  //      FULLY UNROLLED: all 12 float4 loads issue before first consumer. ----
#pragma unroll
  for (int wr = 0; wr < 6; ++wr) {
    int r_img = rowgrp * 4 - 1 + wr;
    int own = r_img - rowgrp * 4;      // 0..3 when this row belongs to the block
    bool isown = (wr >= 1) && (wr <= 4) && ((unsigned)r_img < 28u);
    if ((unsigned)r_img < 28u) {
#pragma unroll
      for (int it = 0; it < 2; ++it) {
        int u = it * 512 + t;          // 896 units: ci-pair(128) x px4(7)
        if (u < 896) {
          int c2 = (u * 9363) >> 16;   // u/7
          int p4 = u - c2 * 7;
          const float* xb = x + ((size_t)(img * 256 + 2 * c2)) * 784 + r_img * 28 + p4 * 4;
          float4 v0 = *(const float4*)(xb);
          float4 v1 = *(const float4*)(xb + 784);
          float b0v = bsh[2 * c2], b1v = bsh[2 * c2 + 1];
          float lo[4] = {v0.x, v0.y, v0.z, v0.w};
          float hi[4] = {v1.x, v1.y, v1.z, v1.w};
          int pbase = wr * 30 + 1 + p4 * 4;
#pragma unroll
          for (int k = 0; k < 4; ++k) {
            int wp = pbase + k;
            u8 byte = (u8)(f2sign4(lo[k] + b0v) | (f2sign4(hi[k] + b1v) << 4));
            wl[wp * 128 + ((((c2 >> 4) ^ (wp & 7)) << 4) | (c2 & 15))] = byte;
          }
          if (isown) {
            int pxloc = own * 28 + p4 * 4;
            f32x4 s0 = {v0.x, v0.y, v0.z, v0.w};
            f32x4 s1 = {v1.x, v1.y, v1.z, v1.w};
            *(f32x4*)(&xbuf[(2 * c2) * 116 + pxloc])     = s0;
            *(f32x4*)(&xbuf[(2 * c2 + 1) * 116 + pxloc]) = s1;
          }
        }
      }
    }
  }
  __syncthreads();

  // ---- loaders / compute (fp4) ----
  auto LOADB3 = [&](long2v* dst, int s) {        // 2 n-frags x 16B/lane
    int sc = (s < 36) ? s : 0;
    const char* base = (const char*)w1T + (size_t)sc * 8192 + h32 * 4096;
#pragma unroll
    for (int nf = 0; nf < 2; ++nf)
      dst[nf] = *(const long2v*)(base + (ng * 64 + nf * 32 + l31) * 16);
  };
  auto DSA3 = [&](long2v* dst, int s) {          // 2 m-frags x 16B/lane
    int sc = (s < 36) ? s : 0;
    int tap = sc >> 2;
    int c64 = sc & 3;
    int ti = (tap * 11) >> 5;                    // tap/3
    int tapoff = ti * 30 + (tap - 3 * ti);
    int slot = c64 * 2 + h32;
#pragma unroll
    for (int mi = 0; mi < 2; ++mi) {
      int wp = basepix[mi] + tapoff;
      dst[mi] = *(const long2v*)(wl + wp * 128 + ((slot ^ (wp & 7)) << 4));
    }
  };
  auto COMP = [&](long2v* a, long2v* bv) {       // 4 MFMA, fp4 fmt
    __builtin_amdgcn_s_setprio(1);
#pragma unroll
    for (int mi = 0; mi < 2; ++mi) {
      v8i a8 = mkv8(a[mi], zl2);
#pragma unroll
      for (int nf = 0; nf < 2; ++nf)
        acc[mi][nf] = __builtin_amdgcn_mfma_scale_f32_32x32x64_f8f6f4(
            a8, mkv8(bv[nf], zl2), acc[mi][nf],
            4, 4,                        // cbsz = blgp = fp4 e2m1
            0, 0x7F7F7F7Fu, 0, 0x7F7F7F7Fu);
    }
    __builtin_amdgcn_s_setprio(0);
  };

  // ---- conv3x3: 36 phases, A 3-set + B 3-set rotation, no barriers ----
  long2v A0[2], A1[2], A2[2];
  long2v b0[2], b1[2], b2[2];
  DSA3(A0, 0); DSA3(A1, 1); LOADB3(b0, 0); LOADB3(b1, 1);
#pragma unroll 1
  for (int i = 0; i < 12; ++i) {
    int p = i * 3;
    LOADB3(b2, p + 2); DSA3(A2, p + 2); COMP(A0, b0);
    LOADB3(b0, p + 3); DSA3(A0, p + 3); COMP(A1, b1);
    LOADB3(b1, p + 4); DSA3(A1, p + 4); COMP(A2, b2);
  }
  __syncthreads();   // all window reads retired -> reuse win region for act2 (fp4)

  // ---- preload ALL conv1x1 B-sets (L2 latency hides under epilogue-1) ----
  auto LOADB1 = [&](long2v* dst, int sp) {
    const char* base = (const char*)w2T + (size_t)sp * 8192 + h32 * 4096;
#pragma unroll
    for (int nf = 0; nf < 2; ++nf)
      dst[nf] = *(const long2v*)(base + (ng * 64 + nf * 32 + l31) * 16);
  };
  long2v B10[2], B11[2], B12[2], B13[2];
  LOADB1(B10, 0); LOADB1(B11, 1); LOADB1(B12, 2); LOADB1(B13, 3);

  // ---- epilogue 1: out1 = BN(conv)+x(LDS) -> bias/PReLU/bias; act2 fp4 -> LDS ----
  u32 pk[2][2][4][2];
#pragma unroll
  for (int mi = 0; mi < 2; ++mi) {
    int m = mg * 2 + mi;
#pragma unroll
    for (int rp = 0; rp < 4; ++rp) {
      int pixbase = m * 32 + 8 * rp + 4 * h32;
      bool valid = (m < 3) || (rp < 2);
#pragma unroll
      for (int nf = 0; nf < 2; ++nf) {
        int O = Ov[nf];
        float xv[4] = {0.f, 0.f, 0.f, 0.f};
        if (valid) {
          f32x4 xr = *(const f32x4*)(&xbuf[O * 116 + pixbase]);
          xv[0] = xr[0]; xv[1] = xr[1]; xv[2] = xr[2]; xv[3] = xr[3];
        }
        float o1v[4];
        u32 mynibs = 0;
#pragma unroll
        for (int reg = 0; reg < 4; ++reg) {
          float v = acc[mi][nf][rp * 4 + reg] * al1[nf] + bt1[nf] + xv[reg];
          float t1 = v + pA1[nf];
          t1 = (t1 > 0.f) ? t1 : pS1[nf] * t1;
          o1v[reg] = t1 + pB1[nf];
          mynibs |= f2sign4(o1v[reg] + p21[nf]) << (4 * reg);
        }
        u32 partner = __shfl_xor((int)mynibs, 1);
        if ((l31 & 1) == 0) {          // even och lane writes the shared byte
          int c2 = O >> 1;
#pragma unroll
          for (int reg = 0; reg < 4; ++reg) {
            int pix = pixbase + reg;
            u8 byte = (u8)(((mynibs >> (4 * reg)) & 0xF) |
                           (((partner >> (4 * reg)) & 0xF) << 4));
            wl[pix * 128 + ((((c2 >> 4) ^ (pix & 7)) << 4) | (c2 & 15))] = byte;
          }
        }
        pk[mi][nf][rp][0] = (u32)f2b(o1v[0]) | ((u32)f2b(o1v[1]) << 16);
        pk[mi][nf][rp][1] = (u32)f2b(o1v[2]) | ((u32)f2b(o1v[3]) << 16);
      }
    }
  }
#pragma unroll
  for (int mi = 0; mi < 2; ++mi)
#pragma unroll
    for (int nf = 0; nf < 2; ++nf) acc[mi][nf] = zero16;

  asm volatile("s_waitcnt lgkmcnt(0)" ::: "memory");   // act2 LDS stores complete
  __builtin_amdgcn_s_barrier();

  // ---- conv1x1: 4 phases (K=256), A dbuf, B preloaded ----
  auto DSA1 = [&](long2v* dst, int sp) {
    int slot = sp * 2 + h32;
#pragma unroll
    for (int mi = 0; mi < 2; ++mi) {
      int pm = (mg * 2 + mi) * 32 + l31;
      dst[mi] = *(const long2v*)(wl + pm * 128 + ((slot ^ (pm & 7)) << 4));
    }
  };
  DSA1(A0, 0);
  DSA1(A1, 1); COMP(A0, B10);
  DSA1(A0, 2); COMP(A1, B11);
  DSA1(A1, 3); COMP(A0, B12);
  COMP(A1, B13);

  __syncthreads();   // all act2 + xbuf reads retired -> re-alias xbuf as out buffer

  // ---- epilogue 2a: results -> LDS [och][116 f32] (re-using xbuf region) ----
  float* outf = xbuf;
#pragma unroll
  for (int mi = 0; mi < 2; ++mi) {
    int m = mg * 2 + mi;
#pragma unroll
    for (int rp = 0; rp < 4; ++rp) {
      bool valid = (m < 3) || (rp < 2);
      if (!valid) continue;
      int pixbase = m * 32 + 8 * rp + 4 * h32;
#pragma unroll
      for (int nf = 0; nf < 2; ++nf) {
        int O = Ov[nf];
        float res[4];
        res[0] = b2f((u16)(pk[mi][nf][rp][0] & 0xFFFF));
        res[1] = b2f((u16)(pk[mi][nf][rp][0] >> 16));
        res[2] = b2f((u16)(pk[mi][nf][rp][1] & 0xFFFF));
        res[3] = b2f((u16)(pk[mi][nf][rp][1] >> 16));
        f32x4 r4;
#pragma unroll
        for (int reg = 0; reg < 4; ++reg) {
          float v = acc[mi][nf][rp * 4 + reg] * al2[nf] + bt2[nf] + res[reg];
          float t1 = v + pA2[nf];
          t1 = (t1 > 0.f) ? t1 : pS2[nf] * t1;
          r4[reg] = t1 + pB2[nf];
        }
        *(f32x4*)(&outf[O * 116 + pixbase]) = r4;
      }
    }
  }
  __syncthreads();

  // ---- epilogue 2b: coalesced NCHW stores (448B runs along px) ----
  const size_t obase = (size_t)img * 200704 + (size_t)rowgrp * 112;
#pragma unroll
  for (int i = 0; i < 14; ++i) {
    int u = i * 512 + t;               // 7168 units: och(256) x px-quad(28)
    int och = u / 28;
    int q = u - och * 28;
    f32x4 v = *(const f32x4*)(&outf[och * 116 + q * 4]);
    float4 r4 = {v[0], v[1], v[2], v[3]};
    *(float4*)(dout + obase + (size_t)och * 784 + q * 4) = r4;
  }
}

// ---------------- launcher ----------------
extern "C" void kernel_launch(void* const* d_in, const int* in_sizes, int n_in,
                              void* d_out, int out_size, void* d_ws, size_t ws_size,
                              hipStream_t stream) {
  const float* x    = (const float*)d_in[0];
  const float* loss = (const float*)d_in[1];
  const float* b11  = (const float*)d_in[2];
  const float* b12  = (const float*)d_in[3];
  const float* b13  = (const float*)d_in[4];
  const float* b21  = (const float*)d_in[5];
  const float* b22  = (const float*)d_in[6];
  const float* b23  = (const float*)d_in[7];
  const float* w1   = (const float*)d_in[8];
  const float* w2   = (const float*)d_in[9];
  const float* g1   = (const float*)d_in[10];
  const float* be1  = (const float*)d_in[11];
  const float* m1   = (const float*)d_in[12];
  const float* v1   = (const float*)d_in[13];
  const float* g2   = (const float*)d_in[14];
  const float* be2  = (const float*)d_in[15];
  const float* m2   = (const float*)d_in[16];
  const float* v2   = (const float*)d_in[17];
  const float* a1   = (const float*)d_in[18];
  const float* a2   = (const float*)d_in[19];

  char* ws = (char*)d_ws;
  u8*    w1T = (u8*)(ws + 0ull);           // 36 x 8KB = 294,912
  u8*    w2T = (u8*)(ws + 294912ull);      // 4 x 8KB = 32,768
  float* ab  = (float*)(ws + 327680ull);   // 4 x 256 f32

  float* out = (float*)d_out;

  prep_kernel<<<512, 256, 0, stream>>>(w1, w2, g1, be1, m1, v1, g2, be2, m2, v2,
                                       w1T, w2T, ab, out + (out_size - 1), loss);
  fused_kernel<<<224, 512, 0, stream>>>(x, b11, w1T, w2T, ab,
                                        b12, a1, b13, b21, b22, a2, b23, out);
}

// Round 23
// 35.844 us; speedup vs baseline: 1.0229x; 1.0229x over previous
//
#include <hip/hip_runtime.h>
#include <hip/hip_bf16.h>

// BasicBlock (ReActNet) fused pipeline, MI355X gfx950.  FINAL = R21 (35.8us).
// R22's prologue-unroll regressed (36.7) -> reverted. Structure:
//  - prep: fp4 e2m1 sign weights (exact for {-1,0,+1}), BN+scale folded, loss.
//  - fused (224 blocks x 512 thr, 112px x 256och, 1 block/CU):
//      act1 window built in-kernel from x (fp4, XOR-swizzled LDS),
//      x residual stashed in LDS during the same pass,
//      conv3x3 = 36 barrier-free phases of MX-scaled fp4 32x32x64 MFMA
//      (scales=1.0 => exact), A/B 3-set register rotation,
//      epilogue-1 (BN+res+PReLU) -> act2 fp4 in LDS -> conv1x1 (B preloaded)
//      -> epilogue-2 via LDS transpose -> coalesced NCHW f32 stores.
//  - XCD-aware block swizzle (224 = 8x28, bijective).

typedef unsigned short u16;
typedef unsigned char  u8;
typedef unsigned int   u32;
typedef unsigned long long u64;
typedef float f32x4 __attribute__((ext_vector_type(4)));
typedef long  long2v __attribute__((ext_vector_type(2)));
typedef int   v8i  __attribute__((ext_vector_type(8)));
typedef float v16f __attribute__((ext_vector_type(16)));

__device__ __forceinline__ float b2f(u16 u) {
  union { unsigned int i; float f; } c; c.i = ((unsigned int)u) << 16; return c.f;
}
__device__ __forceinline__ u16 f2b(float f) {
  unsigned int u = __builtin_bit_cast(unsigned int, f);
  unsigned int r = (u + 0x7FFFu + ((u >> 16) & 1u)) >> 16;   // RNE
  return (u16)r;
}
__device__ __forceinline__ u32 f2sign4(float v) {  // fp4 e2m1 of sign(v)
  return (v > 0.f) ? 0x2u : ((v < 0.f) ? 0xAu : 0x0u);
}
__device__ __forceinline__ v8i mkv8(long2v a, long2v b) {
  union { long2v l[2]; v8i v; } u; u.l[0] = a; u.l[1] = b; return u.v;
}

// ---- prep: fp4 sign weights (nibble-packed, k-ascending), BN fold, loss ----
__global__ __launch_bounds__(256) void prep_kernel(
    const float* __restrict__ w1, const float* __restrict__ w2,
    const float* __restrict__ g1, const float* __restrict__ be1,
    const float* __restrict__ m1, const float* __restrict__ v1,
    const float* __restrict__ g2, const float* __restrict__ be2,
    const float* __restrict__ m2, const float* __restrict__ v2,
    u8* __restrict__ w1T, u8* __restrict__ w2T,
    float* __restrict__ ab,
    float* __restrict__ lossdst, const float* __restrict__ lossin)
{
  __shared__ float wrow[2304];
  __shared__ float red[256];
  const int t = threadIdx.x;
  const int blk = blockIdx.x;
  float s = 0.f;
  if (blk < 256) {                       // w1 row o: stage coalesced, then pack
    const int o = blk;
    const float4* src = (const float4*)(w1 + o * 2304);
#pragma unroll
    for (int i = 0; i < 3; ++i) {
      int c = i * 256 + t;
      if (c < 576) {
        float4 v = src[c];
        wrow[c * 4 + 0] = v.x; wrow[c * 4 + 1] = v.y;
        wrow[c * 4 + 2] = v.z; wrow[c * 4 + 3] = v.w;
        s += fabsf(v.x) + fabsf(v.y) + fabsf(v.z) + fabsf(v.w);
      }
    }
  } else {
    const int o = blk - 256;
    float v = w2[o * 256 + t];
    wrow[t] = v;
    s = fabsf(v);
  }
  red[t] = s;
  __syncthreads();
  for (int st = 128; st > 0; st >>= 1) { if (t < st) red[t] += red[t + st]; __syncthreads(); }
  if (blk < 256) {
    const int o = blk;
    for (int it = t; it < 288; it += 256) {   // (tap, ci-octet)
      int tap = it >> 5, ci8 = it & 31;
      u32 pack = 0;
#pragma unroll
      for (int k = 0; k < 8; ++k)
        pack |= f2sign4(wrow[(ci8 * 8 + k) * 9 + tap]) << (4 * k);
      int c64 = ci8 >> 3, kh = (ci8 >> 2) & 1, slot = ci8 & 3;
      *(u32*)(w1T + (size_t)((tap * 4 + c64) * 2 + kh) * 4096 + o * 16 + slot * 4) = pack;
    }
    if (t == 0) {
      float scale = red[0] / 2304.f;
      float inv = g1[o] / sqrtf(v1[o] + 1e-5f);
      ab[o]       = scale * inv;
      ab[256 + o] = be1[o] - m1[o] * inv;
    }
  } else {
    const int o = blk - 256;
    if (t < 32) {
      u32 pack = 0;
#pragma unroll
      for (int k = 0; k < 8; ++k)
        pack |= f2sign4(wrow[t * 8 + k]) << (4 * k);
      int c64 = t >> 3, kh = (t >> 2) & 1, slot = t & 3;
      *(u32*)(w2T + (size_t)(c64 * 2 + kh) * 4096 + o * 16 + slot * 4) = pack;
    }
    if (t == 0) {
      float scale = red[0] / 256.f;
      float inv = g2[o] / sqrtf(v2[o] + 1e-5f);
      ab[512 + o] = scale * inv;
      ab[768 + o] = be2[o] - m2[o] * inv;
    }
  }
  if (blk == 0 && t == 0) lossdst[0] = lossin[0];
}

// ---------------- fused: act1-window(fp4) + conv3x3 + conv1x1 ----------------
__global__ __launch_bounds__(512, 1) void fused_kernel(
    const float* __restrict__ x, const float* __restrict__ b11,
    const u8* __restrict__ w1T, const u8* __restrict__ w2T,
    const float* __restrict__ ab,
    const float* __restrict__ b12, const float* __restrict__ a1,
    const float* __restrict__ b13, const float* __restrict__ b21,
    const float* __restrict__ b22, const float* __restrict__ a2,
    const float* __restrict__ b23,
    float* __restrict__ dout)
{
  // shmem: [0..26112) fp4 window/act2 ; [26112..144896) xbuf [256 och][116 f32]
  // (xbuf re-aliased as out-transpose buffer after the post-conv1x1 barrier).
  __shared__ __align__(16) u8 shmem[144928];
  __shared__ float bsh[256];

  const int t = threadIdx.x;
  const int w = t >> 6;
  const int l = t & 63;
  const int l31 = l & 31;
  const int h32 = l >> 5;              // k-half selector
  const int mg = w & 1;                // m-pair group
  const int ng = w >> 1;               // och quad (64 och)
  // XCD-aware swizzle (224 = 8*28, bijective): each XCD gets 28 contiguous
  // logical blocks (4 whole images) -> halo-sharing neighbors share an L2.
  const int pxblk = (blockIdx.x & 7) * 28 + (blockIdx.x >> 3);
  const int img = pxblk / 7;
  const int rowgrp = pxblk % 7;

  // per-lane epilogue params for nf = 0,1
  float al1[2], bt1[2], pA1[2], pS1[2], pB1[2], p21[2];
  float al2[2], bt2[2], pA2[2], pS2[2], pB2[2];
  int Ov[2];
#pragma unroll
  for (int nf = 0; nf < 2; ++nf) {
    int O = ng * 64 + nf * 32 + l31;
    Ov[nf] = O;
    al1[nf] = ab[O];       bt1[nf] = ab[256 + O];
    al2[nf] = ab[512 + O]; bt2[nf] = ab[768 + O];
    pA1[nf] = b12[O]; pS1[nf] = a1[O]; pB1[nf] = b13[O]; p21[nf] = b21[O];
    pA2[nf] = b22[O]; pS2[nf] = a2[O]; pB2[nf] = b23[O];
  }

  int basepix[2];
#pragma unroll
  for (int mi = 0; mi < 2; ++mi) {
    int pm = (mg * 2 + mi) * 32 + l31;
    int r = (pm * 293) >> 13;          // pm/28
    basepix[mi] = r * 30 + (pm - 28 * r);
  }

  char* wl = (char*)shmem;
  float* xbuf = (float*)(shmem + 26112);   // [256][116]

  v16f acc[2][2];
  v16f zero16 = {0.f,0.f,0.f,0.f,0.f,0.f,0.f,0.f,0.f,0.f,0.f,0.f,0.f,0.f,0.f,0.f};
  f32x4 zero4 = {0.f, 0.f, 0.f, 0.f};
  long2v zl2 = {0, 0};
#pragma unroll
  for (int mi = 0; mi < 2; ++mi)
#pragma unroll
    for (int nf = 0; nf < 2; ++nf) acc[mi][nf] = zero16;

  // ---- prologue A: zero window (this IS the conv padding), stage b11 ----
  if (t < 256) bsh[t] = b11[t];
#pragma unroll
  for (int i = 0; i < 4; ++i) {
    int c = i * 512 + t;
    if (c < 1632) *(f32x4*)(wl + c * 16) = zero4;
  }
  __syncthreads();

  // ---- prologue B: act1 window from x -> fp4 nibbles (XOR-swizzled);
  //      own-block rows also stashed raw f32 into xbuf[och][116] ----
#pragma unroll 1
  for (int wr = 0; wr < 6; ++wr) {
    int r_img = rowgrp * 4 - 1 + wr;
    int own = r_img - rowgrp * 4;      // 0..3 when this row belongs to the block
    bool isown = (wr >= 1) && (wr <= 4) && ((unsigned)r_img < 28u);
    if ((unsigned)r_img < 28u) {
#pragma unroll
      for (int it = 0; it < 2; ++it) {
        int u = it * 512 + t;          // 896 units: ci-pair(128) x px4(7)
        if (u < 896) {
          int c2 = (u * 9363) >> 16;   // u/7
          int p4 = u - c2 * 7;
          const float* xb = x + ((size_t)(img * 256 + 2 * c2)) * 784 + r_img * 28 + p4 * 4;
          float4 v0 = *(const float4*)(xb);
          float4 v1 = *(const float4*)(xb + 784);
          float b0v = bsh[2 * c2], b1v = bsh[2 * c2 + 1];
          float lo[4] = {v0.x, v0.y, v0.z, v0.w};
          float hi[4] = {v1.x, v1.y, v1.z, v1.w};
          int pbase = wr * 30 + 1 + p4 * 4;
#pragma unroll
          for (int k = 0; k < 4; ++k) {
            int wp = pbase + k;
            u8 byte = (u8)(f2sign4(lo[k] + b0v) | (f2sign4(hi[k] + b1v) << 4));
            wl[wp * 128 + ((((c2 >> 4) ^ (wp & 7)) << 4) | (c2 & 15))] = byte;
          }
          if (isown) {
            int pxloc = own * 28 + p4 * 4;
            f32x4 s0 = {v0.x, v0.y, v0.z, v0.w};
            f32x4 s1 = {v1.x, v1.y, v1.z, v1.w};
            *(f32x4*)(&xbuf[(2 * c2) * 116 + pxloc])     = s0;
            *(f32x4*)(&xbuf[(2 * c2 + 1) * 116 + pxloc]) = s1;
          }
        }
      }
    }
  }
  __syncthreads();

  // ---- loaders / compute (fp4) ----
  auto LOADB3 = [&](long2v* dst, int s) {        // 2 n-frags x 16B/lane
    int sc = (s < 36) ? s : 0;
    const char* base = (const char*)w1T + (size_t)sc * 8192 + h32 * 4096;
#pragma unroll
    for (int nf = 0; nf < 2; ++nf)
      dst[nf] = *(const long2v*)(base + (ng * 64 + nf * 32 + l31) * 16);
  };
  auto DSA3 = [&](long2v* dst, int s) {          // 2 m-frags x 16B/lane
    int sc = (s < 36) ? s : 0;
    int tap = sc >> 2;
    int c64 = sc & 3;
    int ti = (tap * 11) >> 5;                    // tap/3
    int tapoff = ti * 30 + (tap - 3 * ti);
    int slot = c64 * 2 + h32;
#pragma unroll
    for (int mi = 0; mi < 2; ++mi) {
      int wp = basepix[mi] + tapoff;
      dst[mi] = *(const long2v*)(wl + wp * 128 + ((slot ^ (wp & 7)) << 4));
    }
  };
  auto COMP = [&](long2v* a, long2v* bv) {       // 4 MFMA, fp4 fmt
    __builtin_amdgcn_s_setprio(1);
#pragma unroll
    for (int mi = 0; mi < 2; ++mi) {
      v8i a8 = mkv8(a[mi], zl2);
#pragma unroll
      for (int nf = 0; nf < 2; ++nf)
        acc[mi][nf] = __builtin_amdgcn_mfma_scale_f32_32x32x64_f8f6f4(
            a8, mkv8(bv[nf], zl2), acc[mi][nf],
            4, 4,                        // cbsz = blgp = fp4 e2m1
            0, 0x7F7F7F7Fu, 0, 0x7F7F7F7Fu);
    }
    __builtin_amdgcn_s_setprio(0);
  };

  // ---- conv3x3: 36 phases, A 3-set + B 3-set rotation, no barriers ----
  long2v A0[2], A1[2], A2[2];
  long2v b0[2], b1[2], b2[2];
  DSA3(A0, 0); DSA3(A1, 1); LOADB3(b0, 0); LOADB3(b1, 1);
#pragma unroll 1
  for (int i = 0; i < 12; ++i) {
    int p = i * 3;
    LOADB3(b2, p + 2); DSA3(A2, p + 2); COMP(A0, b0);
    LOADB3(b0, p + 3); DSA3(A0, p + 3); COMP(A1, b1);
    LOADB3(b1, p + 4); DSA3(A1, p + 4); COMP(A2, b2);
  }
  __syncthreads();   // all window reads retired -> reuse win region for act2 (fp4)

  // ---- preload ALL conv1x1 B-sets (L2 latency hides under epilogue-1) ----
  auto LOADB1 = [&](long2v* dst, int sp) {
    const char* base = (const char*)w2T + (size_t)sp * 8192 + h32 * 4096;
#pragma unroll
    for (int nf = 0; nf < 2; ++nf)
      dst[nf] = *(const long2v*)(base + (ng * 64 + nf * 32 + l31) * 16);
  };
  long2v B10[2], B11[2], B12[2], B13[2];
  LOADB1(B10, 0); LOADB1(B11, 1); LOADB1(B12, 2); LOADB1(B13, 3);

  // ---- epilogue 1: out1 = BN(conv)+x(LDS) -> bias/PReLU/bias; act2 fp4 -> LDS ----
  u32 pk[2][2][4][2];
#pragma unroll
  for (int mi = 0; mi < 2; ++mi) {
    int m = mg * 2 + mi;
#pragma unroll
    for (int rp = 0; rp < 4; ++rp) {
      int pixbase = m * 32 + 8 * rp + 4 * h32;
      bool valid = (m < 3) || (rp < 2);
#pragma unroll
      for (int nf = 0; nf < 2; ++nf) {
        int O = Ov[nf];
        float xv[4] = {0.f, 0.f, 0.f, 0.f};
        if (valid) {
          f32x4 xr = *(const f32x4*)(&xbuf[O * 116 + pixbase]);
          xv[0] = xr[0]; xv[1] = xr[1]; xv[2] = xr[2]; xv[3] = xr[3];
        }
        float o1v[4];
        u32 mynibs = 0;
#pragma unroll
        for (int reg = 0; reg < 4; ++reg) {
          float v = acc[mi][nf][rp * 4 + reg] * al1[nf] + bt1[nf] + xv[reg];
          float t1 = v + pA1[nf];
          t1 = (t1 > 0.f) ? t1 : pS1[nf] * t1;
          o1v[reg] = t1 + pB1[nf];
          mynibs |= f2sign4(o1v[reg] + p21[nf]) << (4 * reg);
        }
        u32 partner = __shfl_xor((int)mynibs, 1);
        if ((l31 & 1) == 0) {          // even och lane writes the shared byte
          int c2 = O >> 1;
#pragma unroll
          for (int reg = 0; reg < 4; ++reg) {
            int pix = pixbase + reg;
            u8 byte = (u8)(((mynibs >> (4 * reg)) & 0xF) |
                           (((partner >> (4 * reg)) & 0xF) << 4));
            wl[pix * 128 + ((((c2 >> 4) ^ (pix & 7)) << 4) | (c2 & 15))] = byte;
          }
        }
        pk[mi][nf][rp][0] = (u32)f2b(o1v[0]) | ((u32)f2b(o1v[1]) << 16);
        pk[mi][nf][rp][1] = (u32)f2b(o1v[2]) | ((u32)f2b(o1v[3]) << 16);
      }
    }
  }
#pragma unroll
  for (int mi = 0; mi < 2; ++mi)
#pragma unroll
    for (int nf = 0; nf < 2; ++nf) acc[mi][nf] = zero16;

  asm volatile("s_waitcnt lgkmcnt(0)" ::: "memory");   // act2 LDS stores complete
  __builtin_amdgcn_s_barrier();

  // ---- conv1x1: 4 phases (K=256), A dbuf, B preloaded ----
  auto DSA1 = [&](long2v* dst, int sp) {
    int slot = sp * 2 + h32;
#pragma unroll
    for (int mi = 0; mi < 2; ++mi) {
      int pm = (mg * 2 + mi) * 32 + l31;
      dst[mi] = *(const long2v*)(wl + pm * 128 + ((slot ^ (pm & 7)) << 4));
    }
  };
  DSA1(A0, 0);
  DSA1(A1, 1); COMP(A0, B10);
  DSA1(A0, 2); COMP(A1, B11);
  DSA1(A1, 3); COMP(A0, B12);
  COMP(A1, B13);

  __syncthreads();   // all act2 + xbuf reads retired -> re-alias xbuf as out buffer

  // ---- epilogue 2a: results -> LDS [och][116 f32] (re-using xbuf region) ----
  float* outf = xbuf;
#pragma unroll
  for (int mi = 0; mi < 2; ++mi) {
    int m = mg * 2 + mi;
#pragma unroll
    for (int rp = 0; rp < 4; ++rp) {
      bool valid = (m < 3) || (rp < 2);
      if (!valid) continue;
      int pixbase = m * 32 + 8 * rp + 4 * h32;
#pragma unroll
      for (int nf = 0; nf < 2; ++nf) {
        int O = Ov[nf];
        float res[4];
        res[0] = b2f((u16)(pk[mi][nf][rp][0] & 0xFFFF));
        res[1] = b2f((u16)(pk[mi][nf][rp][0] >> 16));
        res[2] = b2f((u16)(pk[mi][nf][rp][1] & 0xFFFF));
        res[3] = b2f((u16)(pk[mi][nf][rp][1] >> 16));
        f32x4 r4;
#pragma unroll
        for (int reg = 0; reg < 4; ++reg) {
          float v = acc[mi][nf][rp * 4 + reg] * al2[nf] + bt2[nf] + res[reg];
          float t1 = v + pA2[nf];
          t1 = (t1 > 0.f) ? t1 : pS2[nf] * t1;
          r4[reg] = t1 + pB2[nf];
        }
        *(f32x4*)(&outf[O * 116 + pixbase]) = r4;
      }
    }
  }
  __syncthreads();

  // ---- epilogue 2b: coalesced NCHW stores (448B runs along px) ----
  const size_t obase = (size_t)img * 200704 + (size_t)rowgrp * 112;
#pragma unroll
  for (int i = 0; i < 14; ++i) {
    int u = i * 512 + t;               // 7168 units: och(256) x px-quad(28)
    int och = u / 28;
    int q = u - och * 28;
    f32x4 v = *(const f32x4*)(&outf[och * 116 + q * 4]);
    float4 r4 = {v[0], v[1], v[2], v[3]};
    *(float4*)(dout + obase + (size_t)och * 784 + q * 4) = r4;
  }
}

// ---------------- launcher ----------------
extern "C" void kernel_launch(void* const* d_in, const int* in_sizes, int n_in,
                              void* d_out, int out_size, void* d_ws, size_t ws_size,
                              hipStream_t stream) {
  const float* x    = (const float*)d_in[0];
  const float* loss = (const float*)d_in[1];
  const float* b11  = (const float*)d_in[2];
  const float* b12  = (const float*)d_in[3];
  const float* b13  = (const float*)d_in[4];
  const float* b21  = (const float*)d_in[5];
  const float* b22  = (const float*)d_in[6];
  const float* b23  = (const float*)d_in[7];
  const float* w1   = (const float*)d_in[8];
  const float* w2   = (const float*)d_in[9];
  const float* g1   = (const float*)d_in[10];
  const float* be1  = (const float*)d_in[11];
  const float* m1   = (const float*)d_in[12];
  const float* v1   = (const float*)d_in[13];
  const float* g2   = (const float*)d_in[14];
  const float* be2  = (const float*)d_in[15];
  const float* m2   = (const float*)d_in[16];
  const float* v2   = (const float*)d_in[17];
  const float* a1   = (const float*)d_in[18];
  const float* a2   = (const float*)d_in[19];

  char* ws = (char*)d_ws;
  u8*    w1T = (u8*)(ws + 0ull);           // 36 x 8KB = 294,912
  u8*    w2T = (u8*)(ws + 294912ull);      // 4 x 8KB = 32,768
  float* ab  = (float*)(ws + 327680ull);   // 4 x 256 f32

  float* out = (float*)d_out;

  prep_kernel<<<512, 256, 0, stream>>>(w1, w2, g1, be1, m1, v1, g2, be2, m2, v2,
                                       w1T, w2T, ab, out + (out_size - 1), loss);
  fused_kernel<<<224, 512, 0, stream>>>(x, b11, w1T, w2T, ab,
                                        b12, a1, b13, b21, b22, a2, b23, out);
}

// Round 25
// 35.650 us; speedup vs baseline: 1.0285x; 1.0055x over previous
//
#include <hip/hip_runtime.h>
#include <hip/hip_bf16.h>

// BasicBlock (ReActNet) fused pipeline, MI355X gfx950.  FINAL = R21 (35.8us,
// reproduced twice, replay-stable). R24 showed removing the s_setprio brackets
// introduces a scheduling-dependent LDS race (post-replay divergence) -- the
// brackets stay. Structure:
//  - prep: fp4 e2m1 sign weights (exact for {-1,0,+1}), BN+scale folded, loss.
//  - fused (224 blocks x 512 thr, 112px x 256och, 1 block/CU):
//      act1 window built in-kernel from x (fp4, XOR-swizzled LDS),
//      x residual stashed in LDS during the same pass,
//      conv3x3 = 36 barrier-free phases of MX-scaled fp4 32x32x64 MFMA
//      (scales=1.0 => exact), A/B 3-set register rotation,
//      epilogue-1 (BN+res+PReLU) -> act2 fp4 in LDS -> conv1x1 (B preloaded)
//      -> epilogue-2 via LDS transpose -> coalesced NCHW f32 stores.
//  - XCD-aware block swizzle (224 = 8x28, bijective).

typedef unsigned short u16;
typedef unsigned char  u8;
typedef unsigned int   u32;
typedef unsigned long long u64;
typedef float f32x4 __attribute__((ext_vector_type(4)));
typedef long  long2v __attribute__((ext_vector_type(2)));
typedef int   v8i  __attribute__((ext_vector_type(8)));
typedef float v16f __attribute__((ext_vector_type(16)));

__device__ __forceinline__ float b2f(u16 u) {
  union { unsigned int i; float f; } c; c.i = ((unsigned int)u) << 16; return c.f;
}
__device__ __forceinline__ u16 f2b(float f) {
  unsigned int u = __builtin_bit_cast(unsigned int, f);
  unsigned int r = (u + 0x7FFFu + ((u >> 16) & 1u)) >> 16;   // RNE
  return (u16)r;
}
__device__ __forceinline__ u32 f2sign4(float v) {  // fp4 e2m1 of sign(v)
  return (v > 0.f) ? 0x2u : ((v < 0.f) ? 0xAu : 0x0u);
}
__device__ __forceinline__ v8i mkv8(long2v a, long2v b) {
  union { long2v l[2]; v8i v; } u; u.l[0] = a; u.l[1] = b; return u.v;
}

// ---- prep: fp4 sign weights (nibble-packed, k-ascending), BN fold, loss ----
__global__ __launch_bounds__(256) void prep_kernel(
    const float* __restrict__ w1, const float* __restrict__ w2,
    const float* __restrict__ g1, const float* __restrict__ be1,
    const float* __restrict__ m1, const float* __restrict__ v1,
    const float* __restrict__ g2, const float* __restrict__ be2,
    const float* __restrict__ m2, const float* __restrict__ v2,
    u8* __restrict__ w1T, u8* __restrict__ w2T,
    float* __restrict__ ab,
    float* __restrict__ lossdst, const float* __restrict__ lossin)
{
  __shared__ float wrow[2304];
  __shared__ float red[256];
  const int t = threadIdx.x;
  const int blk = blockIdx.x;
  float s = 0.f;
  if (blk < 256) {                       // w1 row o: stage coalesced, then pack
    const int o = blk;
    const float4* src = (const float4*)(w1 + o * 2304);
#pragma unroll
    for (int i = 0; i < 3; ++i) {
      int c = i * 256 + t;
      if (c < 576) {
        float4 v = src[c];
        wrow[c * 4 + 0] = v.x; wrow[c * 4 + 1] = v.y;
        wrow[c * 4 + 2] = v.z; wrow[c * 4 + 3] = v.w;
        s += fabsf(v.x) + fabsf(v.y) + fabsf(v.z) + fabsf(v.w);
      }
    }
  } else {
    const int o = blk - 256;
    float v = w2[o * 256 + t];
    wrow[t] = v;
    s = fabsf(v);
  }
  red[t] = s;
  __syncthreads();
  for (int st = 128; st > 0; st >>= 1) { if (t < st) red[t] += red[t + st]; __syncthreads(); }
  if (blk < 256) {
    const int o = blk;
    for (int it = t; it < 288; it += 256) {   // (tap, ci-octet)
      int tap = it >> 5, ci8 = it & 31;
      u32 pack = 0;
#pragma unroll
      for (int k = 0; k < 8; ++k)
        pack |= f2sign4(wrow[(ci8 * 8 + k) * 9 + tap]) << (4 * k);
      int c64 = ci8 >> 3, kh = (ci8 >> 2) & 1, slot = ci8 & 3;
      *(u32*)(w1T + (size_t)((tap * 4 + c64) * 2 + kh) * 4096 + o * 16 + slot * 4) = pack;
    }
    if (t == 0) {
      float scale = red[0] / 2304.f;
      float inv = g1[o] / sqrtf(v1[o] + 1e-5f);
      ab[o]       = scale * inv;
      ab[256 + o] = be1[o] - m1[o] * inv;
    }
  } else {
    const int o = blk - 256;
    if (t < 32) {
      u32 pack = 0;
#pragma unroll
      for (int k = 0; k < 8; ++k)
        pack |= f2sign4(wrow[t * 8 + k]) << (4 * k);
      int c64 = t >> 3, kh = (t >> 2) & 1, slot = t & 3;
      *(u32*)(w2T + (size_t)(c64 * 2 + kh) * 4096 + o * 16 + slot * 4) = pack;
    }
    if (t == 0) {
      float scale = red[0] / 256.f;
      float inv = g2[o] / sqrtf(v2[o] + 1e-5f);
      ab[512 + o] = scale * inv;
      ab[768 + o] = be2[o] - m2[o] * inv;
    }
  }
  if (blk == 0 && t == 0) lossdst[0] = lossin[0];
}

// ---------------- fused: act1-window(fp4) + conv3x3 + conv1x1 ----------------
__global__ __launch_bounds__(512, 1) void fused_kernel(
    const float* __restrict__ x, const float* __restrict__ b11,
    const u8* __restrict__ w1T, const u8* __restrict__ w2T,
    const float* __restrict__ ab,
    const float* __restrict__ b12, const float* __restrict__ a1,
    const float* __restrict__ b13, const float* __restrict__ b21,
    const float* __restrict__ b22, const float* __restrict__ a2,
    const float* __restrict__ b23,
    float* __restrict__ dout)
{
  // shmem: [0..26112) fp4 window/act2 ; [26112..144896) xbuf [256 och][116 f32]
  // (xbuf re-aliased as out-transpose buffer after the post-conv1x1 barrier).
  __shared__ __align__(16) u8 shmem[144928];
  __shared__ float bsh[256];

  const int t = threadIdx.x;
  const int w = t >> 6;
  const int l = t & 63;
  const int l31 = l & 31;
  const int h32 = l >> 5;              // k-half selector
  const int mg = w & 1;                // m-pair group
  const int ng = w >> 1;               // och quad (64 och)
  // XCD-aware swizzle (224 = 8*28, bijective): each XCD gets 28 contiguous
  // logical blocks (4 whole images) -> halo-sharing neighbors share an L2.
  const int pxblk = (blockIdx.x & 7) * 28 + (blockIdx.x >> 3);
  const int img = pxblk / 7;
  const int rowgrp = pxblk % 7;

  // per-lane epilogue params for nf = 0,1
  float al1[2], bt1[2], pA1[2], pS1[2], pB1[2], p21[2];
  float al2[2], bt2[2], pA2[2], pS2[2], pB2[2];
  int Ov[2];
#pragma unroll
  for (int nf = 0; nf < 2; ++nf) {
    int O = ng * 64 + nf * 32 + l31;
    Ov[nf] = O;
    al1[nf] = ab[O];       bt1[nf] = ab[256 + O];
    al2[nf] = ab[512 + O]; bt2[nf] = ab[768 + O];
    pA1[nf] = b12[O]; pS1[nf] = a1[O]; pB1[nf] = b13[O]; p21[nf] = b21[O];
    pA2[nf] = b22[O]; pS2[nf] = a2[O]; pB2[nf] = b23[O];
  }

  int basepix[2];
#pragma unroll
  for (int mi = 0; mi < 2; ++mi) {
    int pm = (mg * 2 + mi) * 32 + l31;
    int r = (pm * 293) >> 13;          // pm/28
    basepix[mi] = r * 30 + (pm - 28 * r);
  }

  char* wl = (char*)shmem;
  float* xbuf = (float*)(shmem + 26112);   // [256][116]

  v16f acc[2][2];
  v16f zero16 = {0.f,0.f,0.f,0.f,0.f,0.f,0.f,0.f,0.f,0.f,0.f,0.f,0.f,0.f,0.f,0.f};
  f32x4 zero4 = {0.f, 0.f, 0.f, 0.f};
  long2v zl2 = {0, 0};
#pragma unroll
  for (int mi = 0; mi < 2; ++mi)
#pragma unroll
    for (int nf = 0; nf < 2; ++nf) acc[mi][nf] = zero16;

  // ---- prologue A: zero window (this IS the conv padding), stage b11 ----
  if (t < 256) bsh[t] = b11[t];
#pragma unroll
  for (int i = 0; i < 4; ++i) {
    int c = i * 512 + t;
    if (c < 1632) *(f32x4*)(wl + c * 16) = zero4;
  }
  __syncthreads();

  // ---- prologue B: act1 window from x -> fp4 nibbles (XOR-swizzled);
  //      own-block rows also stashed raw f32 into xbuf[och][116] ----
#pragma unroll 1
  for (int wr = 0; wr < 6; ++wr) {
    int r_img = rowgrp * 4 - 1 + wr;
    int own = r_img - rowgrp * 4;      // 0..3 when this row belongs to the block
    bool isown = (wr >= 1) && (wr <= 4) && ((unsigned)r_img < 28u);
    if ((unsigned)r_img < 28u) {
#pragma unroll
      for (int it = 0; it < 2; ++it) {
        int u = it * 512 + t;          // 896 units: ci-pair(128) x px4(7)
        if (u < 896) {
          int c2 = (u * 9363) >> 16;   // u/7
          int p4 = u - c2 * 7;
          const float* xb = x + ((size_t)(img * 256 + 2 * c2)) * 784 + r_img * 28 + p4 * 4;
          float4 v0 = *(const float4*)(xb);
          float4 v1 = *(const float4*)(xb + 784);
          float b0v = bsh[2 * c2], b1v = bsh[2 * c2 + 1];
          float lo[4] = {v0.x, v0.y, v0.z, v0.w};
          float hi[4] = {v1.x, v1.y, v1.z, v1.w};
          int pbase = wr * 30 + 1 + p4 * 4;
#pragma unroll
          for (int k = 0; k < 4; ++k) {
            int wp = pbase + k;
            u8 byte = (u8)(f2sign4(lo[k] + b0v) | (f2sign4(hi[k] + b1v) << 4));
            wl[wp * 128 + ((((c2 >> 4) ^ (wp & 7)) << 4) | (c2 & 15))] = byte;
          }
          if (isown) {
            int pxloc = own * 28 + p4 * 4;
            f32x4 s0 = {v0.x, v0.y, v0.z, v0.w};
            f32x4 s1 = {v1.x, v1.y, v1.z, v1.w};
            *(f32x4*)(&xbuf[(2 * c2) * 116 + pxloc])     = s0;
            *(f32x4*)(&xbuf[(2 * c2 + 1) * 116 + pxloc]) = s1;
          }
        }
      }
    }
  }
  __syncthreads();

  // ---- loaders / compute (fp4) ----
  auto LOADB3 = [&](long2v* dst, int s) {        // 2 n-frags x 16B/lane
    int sc = (s < 36) ? s : 0;
    const char* base = (const char*)w1T + (size_t)sc * 8192 + h32 * 4096;
#pragma unroll
    for (int nf = 0; nf < 2; ++nf)
      dst[nf] = *(const long2v*)(base + (ng * 64 + nf * 32 + l31) * 16);
  };
  auto DSA3 = [&](long2v* dst, int s) {          // 2 m-frags x 16B/lane
    int sc = (s < 36) ? s : 0;
    int tap = sc >> 2;
    int c64 = sc & 3;
    int ti = (tap * 11) >> 5;                    // tap/3
    int tapoff = ti * 30 + (tap - 3 * ti);
    int slot = c64 * 2 + h32;
#pragma unroll
    for (int mi = 0; mi < 2; ++mi) {
      int wp = basepix[mi] + tapoff;
      dst[mi] = *(const long2v*)(wl + wp * 128 + ((slot ^ (wp & 7)) << 4));
    }
  };
  auto COMP = [&](long2v* a, long2v* bv) {       // 4 MFMA, fp4 fmt
    __builtin_amdgcn_s_setprio(1);
#pragma unroll
    for (int mi = 0; mi < 2; ++mi) {
      v8i a8 = mkv8(a[mi], zl2);
#pragma unroll
      for (int nf = 0; nf < 2; ++nf)
        acc[mi][nf] = __builtin_amdgcn_mfma_scale_f32_32x32x64_f8f6f4(
            a8, mkv8(bv[nf], zl2), acc[mi][nf],
            4, 4,                        // cbsz = blgp = fp4 e2m1
            0, 0x7F7F7F7Fu, 0, 0x7F7F7F7Fu);
    }
    __builtin_amdgcn_s_setprio(0);
  };

  // ---- conv3x3: 36 phases, A 3-set + B 3-set rotation, no barriers ----
  long2v A0[2], A1[2], A2[2];
  long2v b0[2], b1[2], b2[2];
  DSA3(A0, 0); DSA3(A1, 1); LOADB3(b0, 0); LOADB3(b1, 1);
#pragma unroll 1
  for (int i = 0; i < 12; ++i) {
    int p = i * 3;
    LOADB3(b2, p + 2); DSA3(A2, p + 2); COMP(A0, b0);
    LOADB3(b0, p + 3); DSA3(A0, p + 3); COMP(A1, b1);
    LOADB3(b1, p + 4); DSA3(A1, p + 4); COMP(A2, b2);
  }
  __syncthreads();   // all window reads retired -> reuse win region for act2 (fp4)

  // ---- preload ALL conv1x1 B-sets (L2 latency hides under epilogue-1) ----
  auto LOADB1 = [&](long2v* dst, int sp) {
    const char* base = (const char*)w2T + (size_t)sp * 8192 + h32 * 4096;
#pragma unroll
    for (int nf = 0; nf < 2; ++nf)
      dst[nf] = *(const long2v*)(base + (ng * 64 + nf * 32 + l31) * 16);
  };
  long2v B10[2], B11[2], B12[2], B13[2];
  LOADB1(B10, 0); LOADB1(B11, 1); LOADB1(B12, 2); LOADB1(B13, 3);

  // ---- epilogue 1: out1 = BN(conv)+x(LDS) -> bias/PReLU/bias; act2 fp4 -> LDS ----
  u32 pk[2][2][4][2];
#pragma unroll
  for (int mi = 0; mi < 2; ++mi) {
    int m = mg * 2 + mi;
#pragma unroll
    for (int rp = 0; rp < 4; ++rp) {
      int pixbase = m * 32 + 8 * rp + 4 * h32;
      bool valid = (m < 3) || (rp < 2);
#pragma unroll
      for (int nf = 0; nf < 2; ++nf) {
        int O = Ov[nf];
        float xv[4] = {0.f, 0.f, 0.f, 0.f};
        if (valid) {
          f32x4 xr = *(const f32x4*)(&xbuf[O * 116 + pixbase]);
          xv[0] = xr[0]; xv[1] = xr[1]; xv[2] = xr[2]; xv[3] = xr[3];
        }
        float o1v[4];
        u32 mynibs = 0;
#pragma unroll
        for (int reg = 0; reg < 4; ++reg) {
          float v = acc[mi][nf][rp * 4 + reg] * al1[nf] + bt1[nf] + xv[reg];
          float t1 = v + pA1[nf];
          t1 = (t1 > 0.f) ? t1 : pS1[nf] * t1;
          o1v[reg] = t1 + pB1[nf];
          mynibs |= f2sign4(o1v[reg] + p21[nf]) << (4 * reg);
        }
        u32 partner = __shfl_xor((int)mynibs, 1);
        if ((l31 & 1) == 0) {          // even och lane writes the shared byte
          int c2 = O >> 1;
#pragma unroll
          for (int reg = 0; reg < 4; ++reg) {
            int pix = pixbase + reg;
            u8 byte = (u8)(((mynibs >> (4 * reg)) & 0xF) |
                           (((partner >> (4 * reg)) & 0xF) << 4));
            wl[pix * 128 + ((((c2 >> 4) ^ (pix & 7)) << 4) | (c2 & 15))] = byte;
          }
        }
        pk[mi][nf][rp][0] = (u32)f2b(o1v[0]) | ((u32)f2b(o1v[1]) << 16);
        pk[mi][nf][rp][1] = (u32)f2b(o1v[2]) | ((u32)f2b(o1v[3]) << 16);
      }
    }
  }
#pragma unroll
  for (int mi = 0; mi < 2; ++mi)
#pragma unroll
    for (int nf = 0; nf < 2; ++nf) acc[mi][nf] = zero16;

  asm volatile("s_waitcnt lgkmcnt(0)" ::: "memory");   // act2 LDS stores complete
  __builtin_amdgcn_s_barrier();

  // ---- conv1x1: 4 phases (K=256), A dbuf, B preloaded ----
  auto DSA1 = [&](long2v* dst, int sp) {
    int slot = sp * 2 + h32;
#pragma unroll
    for (int mi = 0; mi < 2; ++mi) {
      int pm = (mg * 2 + mi) * 32 + l31;
      dst[mi] = *(const long2v*)(wl + pm * 128 + ((slot ^ (pm & 7)) << 4));
    }
  };
  DSA1(A0, 0);
  DSA1(A1, 1); COMP(A0, B10);
  DSA1(A0, 2); COMP(A1, B11);
  DSA1(A1, 3); COMP(A0, B12);
  COMP(A1, B13);

  __syncthreads();   // all act2 + xbuf reads retired -> re-alias xbuf as out buffer

  // ---- epilogue 2a: results -> LDS [och][116 f32] (re-using xbuf region) ----
  float* outf = xbuf;
#pragma unroll
  for (int mi = 0; mi < 2; ++mi) {
    int m = mg * 2 + mi;
#pragma unroll
    for (int rp = 0; rp < 4; ++rp) {
      bool valid = (m < 3) || (rp < 2);
      if (!valid) continue;
      int pixbase = m * 32 + 8 * rp + 4 * h32;
#pragma unroll
      for (int nf = 0; nf < 2; ++nf) {
        int O = Ov[nf];
        float res[4];
        res[0] = b2f((u16)(pk[mi][nf][rp][0] & 0xFFFF));
        res[1] = b2f((u16)(pk[mi][nf][rp][0] >> 16));
        res[2] = b2f((u16)(pk[mi][nf][rp][1] & 0xFFFF));
        res[3] = b2f((u16)(pk[mi][nf][rp][1] >> 16));
        f32x4 r4;
#pragma unroll
        for (int reg = 0; reg < 4; ++reg) {
          float v = acc[mi][nf][rp * 4 + reg] * al2[nf] + bt2[nf] + res[reg];
          float t1 = v + pA2[nf];
          t1 = (t1 > 0.f) ? t1 : pS2[nf] * t1;
          r4[reg] = t1 + pB2[nf];
        }
        *(f32x4*)(&outf[O * 116 + pixbase]) = r4;
      }
    }
  }
  __syncthreads();

  // ---- epilogue 2b: coalesced NCHW stores (448B runs along px) ----
  const size_t obase = (size_t)img * 200704 + (size_t)rowgrp * 112;
#pragma unroll
  for (int i = 0; i < 14; ++i) {
    int u = i * 512 + t;               // 7168 units: och(256) x px-quad(28)
    int och = u / 28;
    int q = u - och * 28;
    f32x4 v = *(const f32x4*)(&outf[och * 116 + q * 4]);
    float4 r4 = {v[0], v[1], v[2], v[3]};
    *(float4*)(dout + obase + (size_t)och * 784 + q * 4) = r4;
  }
}

// ---------------- launcher ----------------
extern "C" void kernel_launch(void* const* d_in, const int* in_sizes, int n_in,
                              void* d_out, int out_size, void* d_ws, size_t ws_size,
                              hipStream_t stream) {
  const float* x    = (const float*)d_in[0];
  const float* loss = (const float*)d_in[1];
  const float* b11  = (const float*)d_in[2];
  const float* b12  = (const float*)d_in[3];
  const float* b13  = (const float*)d_in[4];
  const float* b21  = (const float*)d_in[5];
  const float* b22  = (const float*)d_in[6];
  const float* b23  = (const float*)d_in[7];
  const float* w1   = (const float*)d_in[8];
  const float* w2   = (const float*)d_in[9];
  const float* g1   = (const float*)d_in[10];
  const float* be1  = (const float*)d_in[11];
  const float* m1   = (const float*)d_in[12];
  const float* v1   = (const float*)d_in[13];
  const float* g2   = (const float*)d_in[14];
  const float* be2  = (const float*)d_in[15];
  const float* m2   = (const float*)d_in[16];
  const float* v2   = (const float*)d_in[17];
  const float* a1   = (const float*)d_in[18];
  const float* a2   = (const float*)d_in[19];

  char* ws = (char*)d_ws;
  u8*    w1T = (u8*)(ws + 0ull);           // 36 x 8KB = 294,912
  u8*    w2T = (u8*)(ws + 294912ull);      // 4 x 8KB = 32,768
  float* ab  = (float*)(ws + 327680ull);   // 4 x 256 f32

  float* out = (float*)d_out;

  prep_kernel<<<512, 256, 0, stream>>>(w1, w2, g1, be1, m1, v1, g2, be2, m2, v2,
                                       w1T, w2T, ab, out + (out_size - 1), loss);
  fused_kernel<<<224, 512, 0, stream>>>(x, b11, w1T, w2T, ab,
                                        b12, a1, b13, b21, b22, a2, b23, out);
}